// Round 1
// baseline (735.074 us; speedup 1.0000x reference)
//
#include <hip/hip_runtime.h>
#include <stdint.h>

#define D_MODEL 1024
#define NHEAD 16
#define DH 64
#define DFF 4096
#define BATCH 4
#define SEQ 2048
#define MTOT (BATCH*SEQ)   // 8192 rows total

typedef short short8 __attribute__((ext_vector_type(8)));
typedef float f32x4 __attribute__((ext_vector_type(4)));

__device__ inline unsigned short f2bf(float f) {
  union { float f; unsigned u; } v; v.f = f;
  unsigned r = v.u + 0x7fffu + ((v.u >> 16) & 1u);
  return (unsigned short)(r >> 16);
}

// ---------------- cast x -> bf16 ----------------
__global__ void cast_kernel(const float* __restrict__ in, unsigned short* __restrict__ out, int n4) {
  int i = blockIdx.x * blockDim.x + threadIdx.x;
  if (i < n4) {
    float4 v = ((const float4*)in)[i];
    ushort4 o;
    o.x = f2bf(v.x); o.y = f2bf(v.y); o.z = f2bf(v.z); o.w = f2bf(v.w);
    ((ushort4*)out)[i] = o;
  }
}

// ------------- transpose+cast: in [K][N] f32 -> out [N][K] bf16 -------------
__global__ void transpose_cast_kernel(const float* __restrict__ in, unsigned short* __restrict__ out,
                                      int K, int N) {
  __shared__ unsigned short tile[32][33];
  int n0 = blockIdx.x * 32, k0 = blockIdx.y * 32;
  int tx = threadIdx.x & 31, ty = threadIdx.x >> 5;  // 32 x 8
#pragma unroll
  for (int j = 0; j < 32; j += 8)
    tile[ty + j][tx] = f2bf(in[(size_t)(k0 + ty + j) * N + n0 + tx]);
  __syncthreads();
#pragma unroll
  for (int j = 0; j < 32; j += 8)
    out[(size_t)(n0 + ty + j) * K + k0 + tx] = tile[tx][ty + j];
}

// ------------- GEMM: C[M][N] = A[M][K] * Bt[N][K]^T + bias -------------
// A, Bt bf16 (k-major both). 128x128 tile, BK=32, 4 waves, 4x4 16x16x32 MFMA per wave.
template<int RELU, int OUT_BF16>
__global__ __launch_bounds__(256, 2) void gemm_bt_kernel(
    const unsigned short* __restrict__ A,
    const unsigned short* __restrict__ Bt,
    const float* __restrict__ bias,
    void* __restrict__ Cout,
    int M, int N, int K) {
  __shared__ __align__(16) unsigned short As[128][40];
  __shared__ __align__(16) unsigned short Bs[128][40];
  const int m0 = blockIdx.y * 128, n0 = blockIdx.x * 128;
  const int tid = threadIdx.x;
  const int wave = tid >> 6, lane = tid & 63;
  const int wm = (wave >> 1) * 64, wn = (wave & 1) * 64;
  const int lm = lane & 15, lq = lane >> 4, lk = (lane >> 4) * 8;
  const int sr = tid >> 2;          // staging row 0..63 (+64 on 2nd pass)
  const int sc = (tid & 3) * 8;     // staging col {0,8,16,24}
  f32x4 acc[4][4] = {};

  for (int k0 = 0; k0 < K; k0 += 32) {
    __syncthreads();
#pragma unroll
    for (int s = 0; s < 2; s++) {
      int row = sr + s * 64;
      *(uint4*)(&As[row][sc]) = *(const uint4*)(A + (size_t)(m0 + row) * K + k0 + sc);
      *(uint4*)(&Bs[row][sc]) = *(const uint4*)(Bt + (size_t)(n0 + row) * K + k0 + sc);
    }
    __syncthreads();
    short8 af[4], bfr[4];
#pragma unroll
    for (int t = 0; t < 4; t++) {
      af[t]  = *(const short8*)(&As[wm + t * 16 + lm][lk]);
      bfr[t] = *(const short8*)(&Bs[wn + t * 16 + lm][lk]);
    }
#pragma unroll
    for (int mt = 0; mt < 4; mt++)
#pragma unroll
      for (int nt = 0; nt < 4; nt++)
        acc[mt][nt] = __builtin_amdgcn_mfma_f32_16x16x32_bf16(af[mt], bfr[nt], acc[mt][nt], 0, 0, 0);
  }
  // epilogue: C/D layout col=lane&15, row=(lane>>4)*4+r
#pragma unroll
  for (int nt = 0; nt < 4; nt++) {
    int col = n0 + wn + nt * 16 + lm;
    float bv = bias[col];
#pragma unroll
    for (int mt = 0; mt < 4; mt++) {
#pragma unroll
      for (int r = 0; r < 4; r++) {
        int row = m0 + wm + mt * 16 + lq * 4 + r;
        float v = acc[mt][nt][r] + bv;
        if (RELU) v = fmaxf(v, 0.0f);
        if (OUT_BF16) ((unsigned short*)Cout)[(size_t)row * N + col] = f2bf(v);
        else          ((float*)Cout)[(size_t)row * N + col] = v;
      }
    }
  }
}

// ------------- attention: per (b,h,q-tile of 64). softmax(clip(QK^T/8)) V -------------
// clip(+-10) => fixed max 10, no online softmax needed: p=exp(s-10), normalize at end.
__global__ __launch_bounds__(256, 2) void attn_kernel(
    const unsigned short* __restrict__ Q,
    const unsigned short* __restrict__ Kg,
    const unsigned short* __restrict__ Vg,
    unsigned short* __restrict__ ctx) {
  __shared__ __align__(16) unsigned short Ks[64][72];
  __shared__ __align__(16) unsigned short Vt[64][72];     // [dh][kv]
  __shared__ __align__(16) unsigned short Ps[4][16][72];  // per-wave P tile [q][kv]
  const int b = blockIdx.z, h = blockIdx.y, q0 = blockIdx.x * 64;
  const int tid = threadIdx.x, wave = tid >> 6, lane = tid & 63;
  const int lm = lane & 15, lq = lane >> 4, lk = (lane >> 4) * 8;
  const int vr = tid >> 3, vc = (tid & 7) * 8;

  short8 qf[2];
  {
    const unsigned short* qp = Q + (size_t)(b * SEQ + q0 + wave * 16 + lm) * D_MODEL + h * DH;
    qf[0] = *(const short8*)(qp + lk);
    qf[1] = *(const short8*)(qp + 32 + lk);
  }
  f32x4 o_acc[4] = {};
  float l_part[4] = {0.f, 0.f, 0.f, 0.f};

  for (int kv0 = 0; kv0 < SEQ; kv0 += 64) {
    __syncthreads();
#pragma unroll
    for (int s = 0; s < 2; s++) {
      int row = vr + s * 32;
      const size_t goff = (size_t)(b * SEQ + kv0 + row) * D_MODEL + h * DH + vc;
      *(uint4*)(&Ks[row][vc]) = *(const uint4*)(Kg + goff);
      uint4 vv = *(const uint4*)(Vg + goff);
      const unsigned short* vs = (const unsigned short*)&vv;
#pragma unroll
      for (int j = 0; j < 8; j++) Vt[vc + j][row] = vs[j];
    }
    __syncthreads();

    // S = Q K^T (per wave: 16 q-rows x 64 kv)
#pragma unroll
    for (int nt = 0; nt < 4; nt++) {
      f32x4 sacc = {0.f, 0.f, 0.f, 0.f};
      short8 kf0 = *(const short8*)(&Ks[nt * 16 + lm][lk]);
      short8 kf1 = *(const short8*)(&Ks[nt * 16 + lm][32 + lk]);
      sacc = __builtin_amdgcn_mfma_f32_16x16x32_bf16(qf[0], kf0, sacc, 0, 0, 0);
      sacc = __builtin_amdgcn_mfma_f32_16x16x32_bf16(qf[1], kf1, sacc, 0, 0, 0);
#pragma unroll
      for (int r = 0; r < 4; r++) {
        float sv = sacc[r] * 0.125f;
        sv = fminf(fmaxf(sv, -10.0f), 10.0f);
        float p = __expf(sv - 10.0f);
        l_part[r] += p;
        Ps[wave][lq * 4 + r][nt * 16 + lm] = f2bf(p);
      }
    }
    __syncthreads();  // safety: P C/D->A layout round-trip
    short8 pf0 = *(const short8*)(&Ps[wave][lm][lk]);
    short8 pf1 = *(const short8*)(&Ps[wave][lm][32 + lk]);
#pragma unroll
    for (int nt = 0; nt < 4; nt++) {
      short8 vf0 = *(const short8*)(&Vt[nt * 16 + lm][lk]);
      short8 vf1 = *(const short8*)(&Vt[nt * 16 + lm][32 + lk]);
      o_acc[nt] = __builtin_amdgcn_mfma_f32_16x16x32_bf16(pf0, vf0, o_acc[nt], 0, 0, 0);
      o_acc[nt] = __builtin_amdgcn_mfma_f32_16x16x32_bf16(pf1, vf1, o_acc[nt], 0, 0, 0);
    }
  }
  // full row sums across the 16 lanes holding each row
  float l[4];
#pragma unroll
  for (int r = 0; r < 4; r++) {
    float v = l_part[r];
    v += __shfl_xor(v, 1); v += __shfl_xor(v, 2);
    v += __shfl_xor(v, 4); v += __shfl_xor(v, 8);
    l[r] = v;
  }
#pragma unroll
  for (int nt = 0; nt < 4; nt++) {
#pragma unroll
    for (int r = 0; r < 4; r++) {
      int row = q0 + wave * 16 + lq * 4 + r;
      int col = nt * 16 + lm;
      ctx[(size_t)(b * SEQ + row) * D_MODEL + h * DH + col] = f2bf(o_acc[nt][r] / l[r]);
    }
  }
}

// ------------- residual + layernorm (one block per row of 1024) -------------
template<int WRITE_BF16>
__global__ void ln_kernel(const float* __restrict__ A, const float* __restrict__ Bb,
                          const float* __restrict__ gamma, const float* __restrict__ beta,
                          float* __restrict__ outf, unsigned short* __restrict__ outb) {
  const int row = blockIdx.x;
  const int tid = threadIdx.x;
  const size_t base = (size_t)row * D_MODEL + tid * 4;
  float4 xa = *(const float4*)(A + base);
  float4 xb = *(const float4*)(Bb + base);
  float v0 = xa.x + xb.x, v1 = xa.y + xb.y, v2 = xa.z + xb.z, v3 = xa.w + xb.w;
  float s = v0 + v1 + v2 + v3;
  float sq = v0 * v0 + v1 * v1 + v2 * v2 + v3 * v3;
#pragma unroll
  for (int off = 1; off < 64; off <<= 1) {
    s  += __shfl_xor(s, off);
    sq += __shfl_xor(sq, off);
  }
  __shared__ float red[8];
  int wave = tid >> 6;
  if ((tid & 63) == 0) { red[wave * 2] = s; red[wave * 2 + 1] = sq; }
  __syncthreads();
  s  = red[0] + red[2] + red[4] + red[6];
  sq = red[1] + red[3] + red[5] + red[7];
  float mean = s * (1.0f / D_MODEL);
  float var = sq * (1.0f / D_MODEL) - mean * mean;
  float inv = rsqrtf(var + 1e-8f);
  float4 g  = *(const float4*)(gamma + tid * 4);
  float4 be = *(const float4*)(beta + tid * 4);
  float o0 = (v0 - mean) * inv * g.x + be.x;
  float o1 = (v1 - mean) * inv * g.y + be.y;
  float o2 = (v2 - mean) * inv * g.z + be.z;
  float o3 = (v3 - mean) * inv * g.w + be.w;
  float4 of; of.x = o0; of.y = o1; of.z = o2; of.w = o3;
  *(float4*)(outf + base) = of;
  if (WRITE_BF16) {
    ushort4 ub; ub.x = f2bf(o0); ub.y = f2bf(o1); ub.z = f2bf(o2); ub.w = f2bf(o3);
    *(ushort4*)(outb + base) = ub;
  }
}

extern "C" void kernel_launch(void* const* d_in, const int* in_sizes, int n_in,
                              void* d_out, int out_size, void* d_ws, size_t ws_size,
                              hipStream_t stream) {
  const float* x     = (const float*)d_in[0];
  const float* wq    = (const float*)d_in[1];
  const float* bq    = (const float*)d_in[2];
  const float* wk    = (const float*)d_in[3];
  const float* bk    = (const float*)d_in[4];
  const float* wv    = (const float*)d_in[5];
  const float* bv    = (const float*)d_in[6];
  const float* wo    = (const float*)d_in[7];
  const float* bo    = (const float*)d_in[8];
  const float* w1    = (const float*)d_in[9];
  const float* b1    = (const float*)d_in[10];
  const float* w2    = (const float*)d_in[11];
  const float* b2    = (const float*)d_in[12];
  const float* gamma = (const float*)d_in[13];
  const float* beta  = (const float*)d_in[14];

  char* ws = (char*)d_ws;
  const size_t MB = 1ull << 20;
  // buffer plan (184 MB total, aliasing over dead buffers):
  unsigned short* xb    = (unsigned short*)(ws + 0 * MB);    // 16 MB
  unsigned short* wqT   = (unsigned short*)(ws + 16 * MB);   // 2 MB
  unsigned short* wkT   = (unsigned short*)(ws + 18 * MB);
  unsigned short* wvT   = (unsigned short*)(ws + 20 * MB);
  unsigned short* woT   = (unsigned short*)(ws + 22 * MB);
  unsigned short* w1T   = (unsigned short*)(ws + 24 * MB);   // 8 MB
  unsigned short* w2T   = (unsigned short*)(ws + 32 * MB);   // 8 MB
  unsigned short* Qb    = (unsigned short*)(ws + 40 * MB);   // 16 MB
  unsigned short* Kb    = (unsigned short*)(ws + 56 * MB);   // 16 MB
  unsigned short* Vb    = (unsigned short*)(ws + 72 * MB);   // 16 MB
  unsigned short* ctx   = (unsigned short*)(ws + 88 * MB);   // 16 MB
  float*          attn  = (float*)(ws + 40 * MB);            // 32 MB over dead Q,K
  float*          out1f = (float*)(ws + 104 * MB);           // 32 MB
  unsigned short* out1b = (unsigned short*)(ws + 136 * MB);  // 16 MB
  unsigned short* h1    = (unsigned short*)(ws + 40 * MB);   // 64 MB over dead attn,V,ctx
  float*          ffn   = (float*)(ws + 152 * MB);           // 32 MB

  // preprocessing: casts + weight transposes
  cast_kernel<<<(MTOT * D_MODEL / 4 + 255) / 256, 256, 0, stream>>>(x, xb, MTOT * D_MODEL / 4);
  transpose_cast_kernel<<<dim3(32, 32), 256, 0, stream>>>(wq, wqT, D_MODEL, D_MODEL);
  transpose_cast_kernel<<<dim3(32, 32), 256, 0, stream>>>(wk, wkT, D_MODEL, D_MODEL);
  transpose_cast_kernel<<<dim3(32, 32), 256, 0, stream>>>(wv, wvT, D_MODEL, D_MODEL);
  transpose_cast_kernel<<<dim3(32, 32), 256, 0, stream>>>(wo, woT, D_MODEL, D_MODEL);
  transpose_cast_kernel<<<dim3(128, 32), 256, 0, stream>>>(w1, w1T, D_MODEL, DFF);
  transpose_cast_kernel<<<dim3(32, 128), 256, 0, stream>>>(w2, w2T, DFF, D_MODEL);

  dim3 gD(D_MODEL / 128, MTOT / 128);  // (8, 64)
  gemm_bt_kernel<0, 1><<<gD, 256, 0, stream>>>(xb, wqT, bq, Qb, MTOT, D_MODEL, D_MODEL);
  gemm_bt_kernel<0, 1><<<gD, 256, 0, stream>>>(xb, wkT, bk, Kb, MTOT, D_MODEL, D_MODEL);
  gemm_bt_kernel<0, 1><<<gD, 256, 0, stream>>>(xb, wvT, bv, Vb, MTOT, D_MODEL, D_MODEL);

  attn_kernel<<<dim3(SEQ / 64, NHEAD, BATCH), 256, 0, stream>>>(Qb, Kb, Vb, ctx);

  gemm_bt_kernel<0, 0><<<gD, 256, 0, stream>>>(ctx, woT, bo, attn, MTOT, D_MODEL, D_MODEL);
  ln_kernel<1><<<MTOT, 256, 0, stream>>>(x, attn, gamma, beta, out1f, out1b);
  gemm_bt_kernel<1, 1><<<dim3(DFF / 128, MTOT / 128), 256, 0, stream>>>(out1b, w1T, b1, h1, MTOT, DFF, D_MODEL);
  gemm_bt_kernel<0, 0><<<gD, 256, 0, stream>>>(h1, w2T, b2, ffn, MTOT, D_MODEL, DFF);
  ln_kernel<0><<<MTOT, 256, 0, stream>>>(out1f, ffn, gamma, beta, (float*)d_out, nullptr);
}

// Round 2
// 581.892 us; speedup vs baseline: 1.2632x; 1.2632x over previous
//
#include <hip/hip_runtime.h>
#include <stdint.h>

#define D_MODEL 1024
#define NHEAD 16
#define DH 64
#define DFF 4096
#define BATCH 4
#define SEQ 2048
#define MTOT (BATCH*SEQ)   // 8192 rows total

typedef short short8 __attribute__((ext_vector_type(8)));
typedef float f32x4 __attribute__((ext_vector_type(4)));
typedef unsigned int uint;

__device__ inline unsigned short f2bf(float f) {
  union { float f; unsigned u; } v; v.f = f;
  unsigned r = v.u + 0x7fffu + ((v.u >> 16) & 1u);
  return (unsigned short)(r >> 16);
}
__device__ inline float bf2f(unsigned short b) {
  union { unsigned u; float f; } v; v.u = ((unsigned)b) << 16;
  return v.f;
}
// pack two non-negative floats to two bf16 (round-up-at-half) in one dword: [lo | hi<<16]
__device__ inline unsigned pack_bf16(float lo, float hi) {
  union { float f; unsigned u; } a, b; a.f = lo; b.f = hi;
  return __builtin_amdgcn_perm(b.u + 0x8000u, a.u + 0x8000u, 0x07060302u);
}
// async 16B global -> LDS (wave-uniform base + lane*16 contract)
__device__ __forceinline__ void async16(const unsigned short* g, unsigned short* l) {
  __builtin_amdgcn_global_load_lds(
      (const __attribute__((address_space(1))) unsigned int*)g,
      (__attribute__((address_space(3))) unsigned int*)l, 16, 0, 0);
}

// ---------------- cast x -> bf16 ----------------
__global__ void cast_kernel(const float* __restrict__ in, unsigned short* __restrict__ out, int n4) {
  int i = blockIdx.x * blockDim.x + threadIdx.x;
  if (i < n4) {
    float4 v = ((const float4*)in)[i];
    ushort4 o;
    o.x = f2bf(v.x); o.y = f2bf(v.y); o.z = f2bf(v.z); o.w = f2bf(v.w);
    ((ushort4*)out)[i] = o;
  }
}

// ------------- transpose+cast(+scale): in [K][N] f32 -> out [N][K] bf16 -------------
__global__ void transpose_cast_kernel(const float* __restrict__ in, unsigned short* __restrict__ out,
                                      int K, int N, float scale) {
  __shared__ unsigned short tile[32][33];
  int n0 = blockIdx.x * 32, k0 = blockIdx.y * 32;
  int tx = threadIdx.x & 31, ty = threadIdx.x >> 5;  // 32 x 8
#pragma unroll
  for (int j = 0; j < 32; j += 8)
    tile[ty + j][tx] = f2bf(in[(size_t)(k0 + ty + j) * N + n0 + tx] * scale);
  __syncthreads();
#pragma unroll
  for (int j = 0; j < 32; j += 8)
    out[(size_t)(n0 + ty + j) * K + k0 + tx] = tile[tx][ty + j];
}

// ------------- concat + scale biases into [3072] -------------
__global__ void bias_concat_kernel(const float* __restrict__ bq, const float* __restrict__ bk,
                                   const float* __restrict__ bv, float* __restrict__ o) {
  int i = blockIdx.x * 256 + threadIdx.x;
  if (i < 3 * D_MODEL) {
    float v = (i < D_MODEL) ? bq[i] * 0.125f
            : (i < 2 * D_MODEL) ? bk[i - D_MODEL] : bv[i - 2 * D_MODEL];
    o[i] = v;
  }
}

// ------------- transpose V (from qkv cols 2048..3071) into Vt_g[bh][dh][kv] -------------
__global__ void transpose_v_kernel(const unsigned short* __restrict__ QKV,
                                   unsigned short* __restrict__ Vt) {
  __shared__ unsigned short tile[32][33];
  int bh = blockIdx.z, b = bh >> 4, h = bh & 15;
  int kv0 = blockIdx.x * 32, dh0 = blockIdx.y * 32;
  int tx = threadIdx.x & 31, ty = threadIdx.x >> 5;  // 32 x 8
#pragma unroll
  for (int j = 0; j < 32; j += 8)
    tile[ty + j][tx] = QKV[(size_t)(b * SEQ + kv0 + ty + j) * 3072 + 2048 + h * DH + dh0 + tx];
  __syncthreads();
#pragma unroll
  for (int j = 0; j < 32; j += 8)
    Vt[(size_t)(bh * DH + dh0 + ty + j) * SEQ + kv0 + tx] = tile[tx][ty + j];
}

// ------------- GEMM: C[M][N] = A[M][K] * Bt[N][K]^T + bias (m97-style async staging) -------------
template<int RELU, int OUT_BF16>
__global__ __launch_bounds__(256, 2) void gemm_bt_kernel(
    const unsigned short* __restrict__ A,
    const unsigned short* __restrict__ Bt,
    const float* __restrict__ bias,
    void* __restrict__ Cout,
    int M, int N, int K) {
  __shared__ __align__(16) unsigned short As[128][32];
  __shared__ __align__(16) unsigned short Bs[128][32];
  const int m0 = blockIdx.y * 128, n0 = blockIdx.x * 128;
  const int tid = threadIdx.x;
  const int wave = tid >> 6, lane = tid & 63;
  const int wm = (wave >> 1) * 64, wn = (wave & 1) * 64;
  const int lm = lane & 15, lq = lane >> 4, lk = (lane >> 4) * 8;
  const int sr = tid >> 2;          // staging row 0..63 (+64 on 2nd round)
  const int sc = (tid & 3) * 8;     // staging col {0,8,16,24}
  f32x4 acc[4][4] = {};

  for (int k0 = 0; k0 < K; k0 += 32) {
    __syncthreads();
#pragma unroll
    for (int s = 0; s < 2; s++) {
      int row = sr + s * 64;
      async16(A  + (size_t)(m0 + row) * K + k0 + sc, &As[0][0] + row * 32 + sc);
      async16(Bt + (size_t)(n0 + row) * K + k0 + sc, &Bs[0][0] + row * 32 + sc);
    }
    __syncthreads();
    short8 af[4], bfr[4];
#pragma unroll
    for (int t = 0; t < 4; t++) {
      af[t]  = *(const short8*)(&As[wm + t * 16 + lm][lk]);
      bfr[t] = *(const short8*)(&Bs[wn + t * 16 + lm][lk]);
    }
#pragma unroll
    for (int mt = 0; mt < 4; mt++)
#pragma unroll
      for (int nt = 0; nt < 4; nt++)
        acc[mt][nt] = __builtin_amdgcn_mfma_f32_16x16x32_bf16(af[mt], bfr[nt], acc[mt][nt], 0, 0, 0);
  }
  // epilogue: C/D layout col=lane&15, row=(lane>>4)*4+r
#pragma unroll
  for (int nt = 0; nt < 4; nt++) {
    int col = n0 + wn + nt * 16 + lm;
    float bv = bias[col];
#pragma unroll
    for (int mt = 0; mt < 4; mt++) {
#pragma unroll
      for (int r = 0; r < 4; r++) {
        int row = m0 + wm + mt * 16 + lq * 4 + r;
        float v = acc[mt][nt][r] + bv;
        if (RELU) v = fmaxf(v, 0.0f);
        if (OUT_BF16) ((unsigned short*)Cout)[(size_t)row * N + col] = f2bf(v);
        else          ((float*)Cout)[(size_t)row * N + col] = v;
      }
    }
  }
}

// ------------- attention: block = (bh, 128 q-rows). S^T formulation. -------------
// Q pre-scaled by 0.125 in wq. clip(+-10): p=exp(s-10), normalize at end.
__global__ __launch_bounds__(256, 3) void attn_kernel(
    const unsigned short* __restrict__ QKV,   // [8192][3072]: q|k|v
    const unsigned short* __restrict__ Vt_g,  // [64 bh][64 dh][2048 kv]
    unsigned short* __restrict__ ctx) {       // [8192][1024]
  __shared__ __align__(16) unsigned short Ks[64][72];       // [kv][dh]
  __shared__ __align__(16) unsigned short Vs[64][72];       // [dh][kv]
  __shared__ __align__(16) unsigned short Ps[4][32][72];    // per-wave [q_local][kv]
  const int bh = blockIdx.x, b = bh >> 4, h = bh & 15;
  const int q0 = blockIdx.y * 128;
  const int tid = threadIdx.x, wave = tid >> 6, lane = tid & 63;
  const int lm = lane & 15, lq = lane >> 4;
  const int srow = tid >> 3, scol = (tid & 7) * 8;

  // Q fragments (wave's 32 q-rows, 2 n-tiles x 2 k-slabs), stay in regs
  short8 qf[2][2];
#pragma unroll
  for (int ntq = 0; ntq < 2; ntq++) {
    const unsigned short* qp = QKV + (size_t)(b * SEQ + q0 + wave * 32 + ntq * 16 + lm) * 3072 + h * DH;
#pragma unroll
    for (int sl = 0; sl < 2; sl++) qf[ntq][sl] = *(const short8*)(qp + sl * 32 + lq * 8);
  }
  f32x4 oacc[2][4] = {};
  float lpart[2] = {0.f, 0.f};

  for (int kv0 = 0; kv0 < SEQ; kv0 += 64) {
    __syncthreads();
#pragma unroll
    for (int s = 0; s < 2; s++) {
      int row = srow + s * 32;
      *(uint4*)(&Ks[row][scol]) =
          *(const uint4*)(QKV + (size_t)(b * SEQ + kv0 + row) * 3072 + D_MODEL + h * DH + scol);
      *(uint4*)(&Vs[row][scol]) =
          *(const uint4*)(Vt_g + (size_t)(bh * DH + row) * SEQ + kv0 + scol);
    }
    __syncthreads();

    // S^T = K * Q^T ; exp; pack to Ps (per-wave region, vector b64 writes)
#pragma unroll
    for (int mt = 0; mt < 4; mt++) {
      short8 kf0 = *(const short8*)(&Ks[mt * 16 + lm][lq * 8]);
      short8 kf1 = *(const short8*)(&Ks[mt * 16 + lm][32 + lq * 8]);
#pragma unroll
      for (int ntq = 0; ntq < 2; ntq++) {
        f32x4 sa = {0.f, 0.f, 0.f, 0.f};
        sa = __builtin_amdgcn_mfma_f32_16x16x32_bf16(kf0, qf[ntq][0], sa, 0, 0, 0);
        sa = __builtin_amdgcn_mfma_f32_16x16x32_bf16(kf1, qf[ntq][1], sa, 0, 0, 0);
        float p[4];
#pragma unroll
        for (int r = 0; r < 4; r++) {
          float x = fminf(fmaxf(sa[r], -10.0f), 10.0f);
          p[r] = __expf(x - 10.0f);
          lpart[ntq] += p[r];
        }
        uint2 d;
        d.x = pack_bf16(p[0], p[1]);
        d.y = pack_bf16(p[2], p[3]);
        *(uint2*)(&Ps[wave][ntq * 16 + lm][mt * 16 + lq * 4]) = d;
      }
    }
    // wave-local LDS RAW: wait lgkmcnt(0) only (vmcnt=63, expcnt=7 -> 0xC07F)
    __builtin_amdgcn_s_waitcnt(0xC07F);
    short8 pf[2][2];
#pragma unroll
    for (int mq = 0; mq < 2; mq++)
#pragma unroll
      for (int sl = 0; sl < 2; sl++)
        pf[mq][sl] = *(const short8*)(&Ps[wave][mq * 16 + lm][sl * 32 + lq * 8]);
#pragma unroll
    for (int nt = 0; nt < 4; nt++) {
      short8 vf0 = *(const short8*)(&Vs[nt * 16 + lm][lq * 8]);
      short8 vf1 = *(const short8*)(&Vs[nt * 16 + lm][32 + lq * 8]);
#pragma unroll
      for (int mq = 0; mq < 2; mq++) {
        oacc[mq][nt] = __builtin_amdgcn_mfma_f32_16x16x32_bf16(pf[mq][0], vf0, oacc[mq][nt], 0, 0, 0);
        oacc[mq][nt] = __builtin_amdgcn_mfma_f32_16x16x32_bf16(pf[mq][1], vf1, oacc[mq][nt], 0, 0, 0);
      }
    }
  }

  // softmax denominators: reduce lpart over lq (lanes sharing q=ntq*16+lm)
  float lred[2];
#pragma unroll
  for (int ntq = 0; ntq < 2; ntq++) {
    float v = lpart[ntq];
    v += __shfl_xor(v, 16); v += __shfl_xor(v, 32);
    lred[ntq] = v;
  }
#pragma unroll
  for (int mq = 0; mq < 2; mq++) {
    float linv[4];
#pragma unroll
    for (int r = 0; r < 4; r++) linv[r] = 1.0f / __shfl(lred[mq], lq * 4 + r);
#pragma unroll
    for (int nt = 0; nt < 4; nt++) {
#pragma unroll
      for (int r = 0; r < 4; r++) {
        int row = q0 + wave * 32 + mq * 16 + lq * 4 + r;
        int col = h * DH + nt * 16 + lm;
        ctx[(size_t)(b * SEQ + row) * D_MODEL + col] = f2bf(oacc[mq][nt][r] * linv[r]);
      }
    }
  }
}

// ------------- residual + layernorm (one block per row of 1024) -------------
template<int B_BF16, int WRITE_BF16>
__global__ void ln_kernel(const float* __restrict__ A, const void* __restrict__ Bv,
                          const float* __restrict__ gamma, const float* __restrict__ beta,
                          float* __restrict__ outf, unsigned short* __restrict__ outb) {
  const int row = blockIdx.x;
  const int tid = threadIdx.x;
  const size_t base = (size_t)row * D_MODEL + tid * 4;
  float4 xa = *(const float4*)(A + base);
  float4 xb;
  if (B_BF16) {
    ushort4 u = *(const ushort4*)((const unsigned short*)Bv + base);
    xb.x = bf2f(u.x); xb.y = bf2f(u.y); xb.z = bf2f(u.z); xb.w = bf2f(u.w);
  } else {
    xb = *(const float4*)((const float*)Bv + base);
  }
  float v0 = xa.x + xb.x, v1 = xa.y + xb.y, v2 = xa.z + xb.z, v3 = xa.w + xb.w;
  float s = v0 + v1 + v2 + v3;
  float sq = v0 * v0 + v1 * v1 + v2 * v2 + v3 * v3;
#pragma unroll
  for (int off = 1; off < 64; off <<= 1) {
    s  += __shfl_xor(s, off);
    sq += __shfl_xor(sq, off);
  }
  __shared__ float red[8];
  int wave = tid >> 6;
  if ((tid & 63) == 0) { red[wave * 2] = s; red[wave * 2 + 1] = sq; }
  __syncthreads();
  s  = red[0] + red[2] + red[4] + red[6];
  sq = red[1] + red[3] + red[5] + red[7];
  float mean = s * (1.0f / D_MODEL);
  float var = sq * (1.0f / D_MODEL) - mean * mean;
  float inv = rsqrtf(var + 1e-8f);
  float4 g  = *(const float4*)(gamma + tid * 4);
  float4 be = *(const float4*)(beta + tid * 4);
  float o0 = (v0 - mean) * inv * g.x + be.x;
  float o1 = (v1 - mean) * inv * g.y + be.y;
  float o2 = (v2 - mean) * inv * g.z + be.z;
  float o3 = (v3 - mean) * inv * g.w + be.w;
  float4 of; of.x = o0; of.y = o1; of.z = o2; of.w = o3;
  *(float4*)(outf + base) = of;
  if (WRITE_BF16) {
    ushort4 ub; ub.x = f2bf(o0); ub.y = f2bf(o1); ub.z = f2bf(o2); ub.w = f2bf(o3);
    *(ushort4*)(outb + base) = ub;
  }
}

extern "C" void kernel_launch(void* const* d_in, const int* in_sizes, int n_in,
                              void* d_out, int out_size, void* d_ws, size_t ws_size,
                              hipStream_t stream) {
  const float* x     = (const float*)d_in[0];
  const float* wq    = (const float*)d_in[1];
  const float* bq    = (const float*)d_in[2];
  const float* wk    = (const float*)d_in[3];
  const float* bk    = (const float*)d_in[4];
  const float* wv    = (const float*)d_in[5];
  const float* bv    = (const float*)d_in[6];
  const float* wo    = (const float*)d_in[7];
  const float* bo    = (const float*)d_in[8];
  const float* w1    = (const float*)d_in[9];
  const float* b1    = (const float*)d_in[10];
  const float* w2    = (const float*)d_in[11];
  const float* b2    = (const float*)d_in[12];
  const float* gamma = (const float*)d_in[13];
  const float* beta  = (const float*)d_in[14];

  char* ws = (char*)d_ws;
  const size_t MB = 1ull << 20;
  // buffer plan (169 MB peak, aliasing over dead buffers):
  unsigned short* xb     = (unsigned short*)(ws + 0 * MB);    // 16 MB (dead after QKV gemm)
  unsigned short* out1b  = (unsigned short*)(ws + 0 * MB);    //   reuse xb slot after LN1
  unsigned short* wqkvT  = (unsigned short*)(ws + 16 * MB);   // 6 MB  [3072][1024]
  unsigned short* woT    = (unsigned short*)(ws + 22 * MB);   // 2 MB
  unsigned short* w1T    = (unsigned short*)(ws + 24 * MB);   // 8 MB
  unsigned short* w2T    = (unsigned short*)(ws + 32 * MB);   // 8 MB
  float*          bqkv   = (float*)(ws + 40 * MB);            // 12 KB (1 MB slot)
  unsigned short* qkvb   = (unsigned short*)(ws + 41 * MB);   // 48 MB [8192][3072] (dead after attn)
  float*          attnout= (float*)(ws + 41 * MB);            //   32 MB, reuse after attn
  unsigned short* h1     = (unsigned short*)(ws + 41 * MB);   //   64 MB, reuse after LN1 (41..105)
  unsigned short* Vt_g   = (unsigned short*)(ws + 89 * MB);   // 16 MB (dead after attn)
  unsigned short* ctx    = (unsigned short*)(ws + 105 * MB);  // 16 MB (dead after out-proj)
  unsigned short* ffnb   = (unsigned short*)(ws + 105 * MB);  //   16 MB, reuse after FFN2 launch order
  float*          out1f  = (float*)(ws + 121 * MB);           // 32 MB (live till end)

  // preprocessing
  cast_kernel<<<(MTOT * D_MODEL / 4 + 255) / 256, 256, 0, stream>>>(x, xb, MTOT * D_MODEL / 4);
  // wq scaled by 1/8 (folds QK^T scale); exact power of two, no extra rounding
  transpose_cast_kernel<<<dim3(32, 32), 256, 0, stream>>>(wq, wqkvT, D_MODEL, D_MODEL, 0.125f);
  transpose_cast_kernel<<<dim3(32, 32), 256, 0, stream>>>(wk, wqkvT + 1024 * 1024, D_MODEL, D_MODEL, 1.0f);
  transpose_cast_kernel<<<dim3(32, 32), 256, 0, stream>>>(wv, wqkvT + 2 * 1024 * 1024, D_MODEL, D_MODEL, 1.0f);
  transpose_cast_kernel<<<dim3(32, 32), 256, 0, stream>>>(wo, woT, D_MODEL, D_MODEL, 1.0f);
  transpose_cast_kernel<<<dim3(128, 32), 256, 0, stream>>>(w1, w1T, D_MODEL, DFF, 1.0f);
  transpose_cast_kernel<<<dim3(32, 128), 256, 0, stream>>>(w2, w2T, DFF, D_MODEL, 1.0f);
  bias_concat_kernel<<<12, 256, 0, stream>>>(bq, bk, bv, bqkv);

  // fused QKV projection: [8192][3072]
  gemm_bt_kernel<0, 1><<<dim3(3072 / 128, MTOT / 128), 256, 0, stream>>>(
      xb, wqkvT, bqkv, qkvb, MTOT, 3072, D_MODEL);
  // V -> Vt_g[bh][dh][kv]
  transpose_v_kernel<<<dim3(SEQ / 32, DH / 32, BATCH * NHEAD), 256, 0, stream>>>(qkvb, Vt_g);
  // attention (grid.x = bh for XCD L2 locality: all q-tiles of a head share an XCD)
  attn_kernel<<<dim3(BATCH * NHEAD, SEQ / 128), 256, 0, stream>>>(qkvb, Vt_g, ctx);

  dim3 gD(D_MODEL / 128, MTOT / 128);
  gemm_bt_kernel<0, 0><<<gD, 256, 0, stream>>>(ctx, woT, bo, attnout, MTOT, D_MODEL, D_MODEL);
  ln_kernel<0, 1><<<MTOT, 256, 0, stream>>>(x, attnout, gamma, beta, out1f, out1b);
  gemm_bt_kernel<1, 1><<<dim3(DFF / 128, MTOT / 128), 256, 0, stream>>>(
      out1b, w1T, b1, h1, MTOT, DFF, D_MODEL);
  gemm_bt_kernel<0, 1><<<gD, 256, 0, stream>>>(h1, w2T, b2, ffnb, MTOT, D_MODEL, DFF);
  ln_kernel<1, 0><<<MTOT, 256, 0, stream>>>(out1f, ffnb, gamma, beta, (float*)d_out, nullptr);
}

// Round 3
// 552.500 us; speedup vs baseline: 1.3305x; 1.0532x over previous
//
#include <hip/hip_runtime.h>
#include <stdint.h>

#define D_MODEL 1024
#define NHEAD 16
#define DH 64
#define DFF 4096
#define BATCH 4
#define SEQ 2048
#define MTOT (BATCH*SEQ)   // 8192 rows total

typedef short short8 __attribute__((ext_vector_type(8)));
typedef float f32x4 __attribute__((ext_vector_type(4)));
typedef unsigned int uint;

__device__ inline unsigned short f2bf(float f) {
  union { float f; unsigned u; } v; v.f = f;
  unsigned r = v.u + 0x7fffu + ((v.u >> 16) & 1u);
  return (unsigned short)(r >> 16);
}
__device__ inline float bf2f(unsigned short b) {
  union { unsigned u; float f; } v; v.u = ((unsigned)b) << 16;
  return v.f;
}
// truncation-pack two non-negative floats to bf16 pair in one dword: [lo | hi<<16]
__device__ inline unsigned pack_trunc(float lo, float hi) {
  union { float f; unsigned u; } a, b; a.f = lo; b.f = hi;
  return __builtin_amdgcn_perm(b.u, a.u, 0x07060302u);
}
// async 16B global -> LDS (wave-uniform base + lane*16 contract)
__device__ __forceinline__ void async16(const unsigned short* g, unsigned short* l) {
  __builtin_amdgcn_global_load_lds(
      (const __attribute__((address_space(1))) unsigned int*)g,
      (__attribute__((address_space(3))) unsigned int*)l, 16, 0, 0);
}

// ---------------- cast x -> bf16 ----------------
__global__ void cast_kernel(const float* __restrict__ in, unsigned short* __restrict__ out, int n4) {
  int i = blockIdx.x * blockDim.x + threadIdx.x;
  if (i < n4) {
    float4 v = ((const float4*)in)[i];
    ushort4 o;
    o.x = f2bf(v.x); o.y = f2bf(v.y); o.z = f2bf(v.z); o.w = f2bf(v.w);
    ((ushort4*)out)[i] = o;
  }
}

// ------------- transpose+cast(+scale): in [K][N] f32 -> out [N][K] bf16 -------------
__global__ void transpose_cast_kernel(const float* __restrict__ in, unsigned short* __restrict__ out,
                                      int K, int N, float scale) {
  __shared__ unsigned short tile[32][33];
  int n0 = blockIdx.x * 32, k0 = blockIdx.y * 32;
  int tx = threadIdx.x & 31, ty = threadIdx.x >> 5;  // 32 x 8
#pragma unroll
  for (int j = 0; j < 32; j += 8)
    tile[ty + j][tx] = f2bf(in[(size_t)(k0 + ty + j) * N + n0 + tx] * scale);
  __syncthreads();
#pragma unroll
  for (int j = 0; j < 32; j += 8)
    out[(size_t)(n0 + ty + j) * K + k0 + tx] = tile[tx][ty + j];
}

// ------------- concat + scale biases into [3072] -------------
__global__ void bias_concat_kernel(const float* __restrict__ bq, const float* __restrict__ bk,
                                   const float* __restrict__ bv, float* __restrict__ o) {
  int i = blockIdx.x * 256 + threadIdx.x;
  if (i < 3 * D_MODEL) {
    float v = (i < D_MODEL) ? bq[i] * 0.125f
            : (i < 2 * D_MODEL) ? bk[i - D_MODEL] : bv[i - 2 * D_MODEL];
    o[i] = v;
  }
}

// ------------- transpose V (from qkv cols 2048..3071) into Vt_g[bh][dh][kv] -------------
__global__ void transpose_v_kernel(const unsigned short* __restrict__ QKV,
                                   unsigned short* __restrict__ Vt) {
  __shared__ unsigned short tile[32][33];
  int bh = blockIdx.z, b = bh >> 4, h = bh & 15;
  int kv0 = blockIdx.x * 32, dh0 = blockIdx.y * 32;
  int tx = threadIdx.x & 31, ty = threadIdx.x >> 5;  // 32 x 8
#pragma unroll
  for (int j = 0; j < 32; j += 8)
    tile[ty + j][tx] = QKV[(size_t)(b * SEQ + kv0 + ty + j) * 3072 + 2048 + h * DH + dh0 + tx];
  __syncthreads();
#pragma unroll
  for (int j = 0; j < 32; j += 8)
    Vt[(size_t)(bh * DH + dh0 + ty + j) * SEQ + kv0 + tx] = tile[tx][ty + j];
}

// ------------- GEMM: C[M][N] = A[M][K] * Bt[N][K]^T + bias (m97-style async staging) -------------
template<int RELU, int OUT_BF16>
__global__ __launch_bounds__(256, 2) void gemm_bt_kernel(
    const unsigned short* __restrict__ A,
    const unsigned short* __restrict__ Bt,
    const float* __restrict__ bias,
    void* __restrict__ Cout,
    int M, int N, int K) {
  __shared__ __align__(16) unsigned short As[128][32];
  __shared__ __align__(16) unsigned short Bs[128][32];
  const int m0 = blockIdx.y * 128, n0 = blockIdx.x * 128;
  const int tid = threadIdx.x;
  const int wave = tid >> 6, lane = tid & 63;
  const int wm = (wave >> 1) * 64, wn = (wave & 1) * 64;
  const int lm = lane & 15, lq = lane >> 4, lk = (lane >> 4) * 8;
  const int sr = tid >> 2;          // staging row 0..63 (+64 on 2nd round)
  const int sc = (tid & 3) * 8;     // staging col {0,8,16,24}
  f32x4 acc[4][4] = {};

  for (int k0 = 0; k0 < K; k0 += 32) {
    __syncthreads();
#pragma unroll
    for (int s = 0; s < 2; s++) {
      int row = sr + s * 64;
      async16(A  + (size_t)(m0 + row) * K + k0 + sc, &As[0][0] + row * 32 + sc);
      async16(Bt + (size_t)(n0 + row) * K + k0 + sc, &Bs[0][0] + row * 32 + sc);
    }
    __syncthreads();
    short8 af[4], bfr[4];
#pragma unroll
    for (int t = 0; t < 4; t++) {
      af[t]  = *(const short8*)(&As[wm + t * 16 + lm][lk]);
      bfr[t] = *(const short8*)(&Bs[wn + t * 16 + lm][lk]);
    }
#pragma unroll
    for (int mt = 0; mt < 4; mt++)
#pragma unroll
      for (int nt = 0; nt < 4; nt++)
        acc[mt][nt] = __builtin_amdgcn_mfma_f32_16x16x32_bf16(af[mt], bfr[nt], acc[mt][nt], 0, 0, 0);
  }
  // epilogue: C/D layout col=lane&15, row=(lane>>4)*4+r
#pragma unroll
  for (int nt = 0; nt < 4; nt++) {
    int col = n0 + wn + nt * 16 + lm;
    float bv = bias[col];
#pragma unroll
    for (int mt = 0; mt < 4; mt++) {
#pragma unroll
      for (int r = 0; r < 4; r++) {
        int row = m0 + wm + mt * 16 + lq * 4 + r;
        float v = acc[mt][nt][r] + bv;
        if (RELU) v = fmaxf(v, 0.0f);
        if (OUT_BF16) ((unsigned short*)Cout)[(size_t)row * N + col] = f2bf(v);
        else          ((float*)Cout)[(size_t)row * N + col] = v;
      }
    }
  }
}

// ------------- attention: block = (bh, 128 q-rows). S^T formulation, swizzled LDS. -------------
// Q pre-scaled by 0.125 in wq/bq. Ref clips logits at +-10: we keep min(s,10) (upper);
// lower clip dropped (exp(s) vs exp(-10): both negligible vs rowsum). No -10 shift:
// it cancels in normalization; p <= e^10 = 22026 fits f32/bf16 fine.
// Row sums computed by MFMA against an all-ones B fragment (lands in the same lane/reg
// as the matching oacc rows -> no shuffle reduce).
// LDS layout: unpadded 64-short rows, phys_col = col ^ ((row&7)*8)  (16B-granular XOR
// rotation) -> all access classes spread to the inherent bank multiplicity.
__global__ __launch_bounds__(256, 4) void attn_kernel(
    const unsigned short* __restrict__ QKV,   // [8192][3072]: q|k|v
    const unsigned short* __restrict__ Vt_g,  // [64 bh][64 dh][2048 kv]
    unsigned short* __restrict__ ctx) {       // [8192][1024]
  __shared__ __align__(16) unsigned short Ks[64 * 64];       // [kv][dh] swizzled
  __shared__ __align__(16) unsigned short Vs[64 * 64];       // [dh][kv] swizzled
  __shared__ __align__(16) unsigned short Ps[4 * 32 * 64];   // per-wave [q][kv] swizzled
  const int bh = blockIdx.x, b = bh >> 4, h = bh & 15;
  const int q0 = blockIdx.y * 128;
  const int tid = threadIdx.x, wave = tid >> 6, lane = tid & 63;
  const int lm = lane & 15, lq = lane >> 4;
  const int srow = tid >> 3, scol = (tid & 7) * 8;

  // Q fragments (wave's 32 q-rows, 2 n-tiles x 2 k-slabs), stay in regs
  short8 qf[2][2];
#pragma unroll
  for (int ntq = 0; ntq < 2; ntq++) {
    const unsigned short* qp = QKV + (size_t)(b * SEQ + q0 + wave * 32 + ntq * 16 + lm) * 3072 + h * DH;
#pragma unroll
    for (int sl = 0; sl < 2; sl++) qf[ntq][sl] = *(const short8*)(qp + sl * 32 + lq * 8);
  }
  const short8 ones = {0x3F80, 0x3F80, 0x3F80, 0x3F80, 0x3F80, 0x3F80, 0x3F80, 0x3F80};
  f32x4 oacc[2][4] = {};
  f32x4 lsum[2] = {};

  // staging addresses (row rotation constant: (srow+32)&7 == srow&7)
  const int sdst = srow * 64 + (scol ^ ((srow & 7) * 8));
  const unsigned short* kg = QKV + (size_t)(b * SEQ) * 3072 + D_MODEL + h * DH + scol;
  const unsigned short* vg = Vt_g + (size_t)(bh * DH + srow) * SEQ + scol;
  const int rot = (lm & 7) * 8;

  for (int kv0 = 0; kv0 < SEQ; kv0 += 64) {
    __syncthreads();
    *(uint4*)(Ks + sdst)        = *(const uint4*)(kg + (size_t)(kv0 + srow) * 3072);
    *(uint4*)(Ks + sdst + 2048) = *(const uint4*)(kg + (size_t)(kv0 + srow + 32) * 3072);
    *(uint4*)(Vs + sdst)        = *(const uint4*)(vg + kv0);
    *(uint4*)(Vs + sdst + 2048) = *(const uint4*)(vg + 32 * SEQ + kv0);
    __syncthreads();

    // S^T = K * Q^T ; p = exp(min(s,10)); truncation-pack to Ps
#pragma unroll
    for (int mt = 0; mt < 4; mt++) {
      const unsigned short* krow = Ks + (mt * 16 + lm) * 64;
      short8 kf0 = *(const short8*)(krow + ((lq * 8) ^ rot));
      short8 kf1 = *(const short8*)(krow + ((32 + lq * 8) ^ rot));
#pragma unroll
      for (int ntq = 0; ntq < 2; ntq++) {
        f32x4 sa = {0.f, 0.f, 0.f, 0.f};
        sa = __builtin_amdgcn_mfma_f32_16x16x32_bf16(kf0, qf[ntq][0], sa, 0, 0, 0);
        sa = __builtin_amdgcn_mfma_f32_16x16x32_bf16(kf1, qf[ntq][1], sa, 0, 0, 0);
        float p0 = __expf(fminf(sa[0], 10.0f));
        float p1 = __expf(fminf(sa[1], 10.0f));
        float p2 = __expf(fminf(sa[2], 10.0f));
        float p3 = __expf(fminf(sa[3], 10.0f));
        uint2 d;
        d.x = pack_trunc(p0, p1);
        d.y = pack_trunc(p2, p3);
        *(uint2*)(Ps + wave * 2048 + (ntq * 16 + lm) * 64 + ((mt * 16 + lq * 4) ^ rot)) = d;
      }
    }
    // wave-local LDS RAW: wait lgkmcnt(0) only (vmcnt=63, expcnt=7 -> 0xC07F)
    __builtin_amdgcn_s_waitcnt(0xC07F);
    short8 pf[2][2];
#pragma unroll
    for (int mq = 0; mq < 2; mq++)
#pragma unroll
      for (int sl = 0; sl < 2; sl++)
        pf[mq][sl] = *(const short8*)(Ps + wave * 2048 + (mq * 16 + lm) * 64 + ((sl * 32 + lq * 8) ^ rot));
#pragma unroll
    for (int nt = 0; nt < 4; nt++) {
      const unsigned short* vrow = Vs + (nt * 16 + lm) * 64;
      short8 vf0 = *(const short8*)(vrow + ((lq * 8) ^ rot));
      short8 vf1 = *(const short8*)(vrow + ((32 + lq * 8) ^ rot));
#pragma unroll
      for (int mq = 0; mq < 2; mq++) {
        oacc[mq][nt] = __builtin_amdgcn_mfma_f32_16x16x32_bf16(pf[mq][0], vf0, oacc[mq][nt], 0, 0, 0);
        oacc[mq][nt] = __builtin_amdgcn_mfma_f32_16x16x32_bf16(pf[mq][1], vf1, oacc[mq][nt], 0, 0, 0);
      }
    }
    // row sums: P x ones (D row = lq*4+r matches oacc rows in the same lane)
#pragma unroll
    for (int mq = 0; mq < 2; mq++) {
      lsum[mq] = __builtin_amdgcn_mfma_f32_16x16x32_bf16(pf[mq][0], ones, lsum[mq], 0, 0, 0);
      lsum[mq] = __builtin_amdgcn_mfma_f32_16x16x32_bf16(pf[mq][1], ones, lsum[mq], 0, 0, 0);
    }
  }

#pragma unroll
  for (int mq = 0; mq < 2; mq++) {
    float linv[4];
#pragma unroll
    for (int r = 0; r < 4; r++) linv[r] = 1.0f / lsum[mq][r];
    const size_t rowbase = (size_t)(b * SEQ + q0 + wave * 32 + mq * 16 + lq * 4) * D_MODEL + h * DH;
#pragma unroll
    for (int nt = 0; nt < 4; nt++) {
#pragma unroll
      for (int r = 0; r < 4; r++) {
        ctx[rowbase + (size_t)r * D_MODEL + nt * 16 + lm] = f2bf(oacc[mq][nt][r] * linv[r]);
      }
    }
  }
}

// ------------- residual + layernorm (one block per row of 1024) -------------
template<int B_BF16, int WRITE_BF16>
__global__ void ln_kernel(const float* __restrict__ A, const void* __restrict__ Bv,
                          const float* __restrict__ gamma, const float* __restrict__ beta,
                          float* __restrict__ outf, unsigned short* __restrict__ outb) {
  const int row = blockIdx.x;
  const int tid = threadIdx.x;
  const size_t base = (size_t)row * D_MODEL + tid * 4;
  float4 xa = *(const float4*)(A + base);
  float4 xb;
  if (B_BF16) {
    ushort4 u = *(const ushort4*)((const unsigned short*)Bv + base);
    xb.x = bf2f(u.x); xb.y = bf2f(u.y); xb.z = bf2f(u.z); xb.w = bf2f(u.w);
  } else {
    xb = *(const float4*)((const float*)Bv + base);
  }
  float v0 = xa.x + xb.x, v1 = xa.y + xb.y, v2 = xa.z + xb.z, v3 = xa.w + xb.w;
  float s = v0 + v1 + v2 + v3;
  float sq = v0 * v0 + v1 * v1 + v2 * v2 + v3 * v3;
#pragma unroll
  for (int off = 1; off < 64; off <<= 1) {
    s  += __shfl_xor(s, off);
    sq += __shfl_xor(sq, off);
  }
  __shared__ float red[8];
  int wave = tid >> 6;
  if ((tid & 63) == 0) { red[wave * 2] = s; red[wave * 2 + 1] = sq; }
  __syncthreads();
  s  = red[0] + red[2] + red[4] + red[6];
  sq = red[1] + red[3] + red[5] + red[7];
  float mean = s * (1.0f / D_MODEL);
  float var = sq * (1.0f / D_MODEL) - mean * mean;
  float inv = rsqrtf(var + 1e-8f);
  float4 g  = *(const float4*)(gamma + tid * 4);
  float4 be = *(const float4*)(beta + tid * 4);
  float o0 = (v0 - mean) * inv * g.x + be.x;
  float o1 = (v1 - mean) * inv * g.y + be.y;
  float o2 = (v2 - mean) * inv * g.z + be.z;
  float o3 = (v3 - mean) * inv * g.w + be.w;
  float4 of; of.x = o0; of.y = o1; of.z = o2; of.w = o3;
  *(float4*)(outf + base) = of;
  if (WRITE_BF16) {
    ushort4 ub; ub.x = f2bf(o0); ub.y = f2bf(o1); ub.z = f2bf(o2); ub.w = f2bf(o3);
    *(ushort4*)(outb + base) = ub;
  }
}

extern "C" void kernel_launch(void* const* d_in, const int* in_sizes, int n_in,
                              void* d_out, int out_size, void* d_ws, size_t ws_size,
                              hipStream_t stream) {
  const float* x     = (const float*)d_in[0];
  const float* wq    = (const float*)d_in[1];
  const float* bq    = (const float*)d_in[2];
  const float* wk    = (const float*)d_in[3];
  const float* bk    = (const float*)d_in[4];
  const float* wv    = (const float*)d_in[5];
  const float* bv    = (const float*)d_in[6];
  const float* wo    = (const float*)d_in[7];
  const float* bo    = (const float*)d_in[8];
  const float* w1    = (const float*)d_in[9];
  const float* b1    = (const float*)d_in[10];
  const float* w2    = (const float*)d_in[11];
  const float* b2    = (const float*)d_in[12];
  const float* gamma = (const float*)d_in[13];
  const float* beta  = (const float*)d_in[14];

  char* ws = (char*)d_ws;
  const size_t MB = 1ull << 20;
  // buffer plan (aliasing over dead buffers):
  unsigned short* xb      = (unsigned short*)(ws + 0 * MB);    // 16 MB (dead after QKV gemm)
  unsigned short* out1b   = (unsigned short*)(ws + 0 * MB);    //   reuse xb slot after LN1
  unsigned short* wqkvT   = (unsigned short*)(ws + 16 * MB);   // 6 MB  [3072][1024]
  unsigned short* woT     = (unsigned short*)(ws + 22 * MB);   // 2 MB
  unsigned short* w1T     = (unsigned short*)(ws + 24 * MB);   // 8 MB
  unsigned short* w2T     = (unsigned short*)(ws + 32 * MB);   // 8 MB
  float*          bqkv    = (float*)(ws + 40 * MB);            // 12 KB (1 MB slot)
  unsigned short* qkvb    = (unsigned short*)(ws + 41 * MB);   // 48 MB [8192][3072] (dead after attn)
  unsigned short* attnoutb= (unsigned short*)(ws + 41 * MB);   //   16 MB bf16, reuse after attn
  unsigned short* h1      = (unsigned short*)(ws + 41 * MB);   //   64 MB, reuse after LN1 (41..105)
  unsigned short* Vt_g    = (unsigned short*)(ws + 89 * MB);   // 16 MB (dead after attn)
  unsigned short* ctx     = (unsigned short*)(ws + 105 * MB);  // 16 MB (dead after out-proj)
  unsigned short* ffnb    = (unsigned short*)(ws + 105 * MB);  //   16 MB, reuse
  float*          out1f   = (float*)(ws + 121 * MB);           // 32 MB (live till end)

  // preprocessing
  cast_kernel<<<(MTOT * D_MODEL / 4 + 255) / 256, 256, 0, stream>>>(x, xb, MTOT * D_MODEL / 4);
  // wq scaled by 1/8 (folds QK^T scale); exact power of two, no extra rounding
  transpose_cast_kernel<<<dim3(32, 32), 256, 0, stream>>>(wq, wqkvT, D_MODEL, D_MODEL, 0.125f);
  transpose_cast_kernel<<<dim3(32, 32), 256, 0, stream>>>(wk, wqkvT + 1024 * 1024, D_MODEL, D_MODEL, 1.0f);
  transpose_cast_kernel<<<dim3(32, 32), 256, 0, stream>>>(wv, wqkvT + 2 * 1024 * 1024, D_MODEL, D_MODEL, 1.0f);
  transpose_cast_kernel<<<dim3(32, 32), 256, 0, stream>>>(wo, woT, D_MODEL, D_MODEL, 1.0f);
  transpose_cast_kernel<<<dim3(128, 32), 256, 0, stream>>>(w1, w1T, D_MODEL, DFF, 1.0f);
  transpose_cast_kernel<<<dim3(32, 128), 256, 0, stream>>>(w2, w2T, DFF, D_MODEL, 1.0f);
  bias_concat_kernel<<<12, 256, 0, stream>>>(bq, bk, bv, bqkv);

  // fused QKV projection: [8192][3072]
  gemm_bt_kernel<0, 1><<<dim3(3072 / 128, MTOT / 128), 256, 0, stream>>>(
      xb, wqkvT, bqkv, qkvb, MTOT, 3072, D_MODEL);
  // V -> Vt_g[bh][dh][kv]
  transpose_v_kernel<<<dim3(SEQ / 32, DH / 32, BATCH * NHEAD), 256, 0, stream>>>(qkvb, Vt_g);
  // attention (grid.x = bh: all 16 q-tiles of one bh land on the same XCD -> KV L2-resident)
  attn_kernel<<<dim3(BATCH * NHEAD, SEQ / 128), 256, 0, stream>>>(qkvb, Vt_g, ctx);

  dim3 gD(D_MODEL / 128, MTOT / 128);
  gemm_bt_kernel<0, 1><<<gD, 256, 0, stream>>>(ctx, woT, bo, attnoutb, MTOT, D_MODEL, D_MODEL);
  ln_kernel<1, 1><<<MTOT, 256, 0, stream>>>(x, attnoutb, gamma, beta, out1f, out1b);
  gemm_bt_kernel<1, 1><<<dim3(DFF / 128, MTOT / 128), 256, 0, stream>>>(
      out1b, w1T, b1, h1, MTOT, DFF, D_MODEL);
  gemm_bt_kernel<0, 1><<<gD, 256, 0, stream>>>(h1, w2T, b2, ffnb, MTOT, D_MODEL, DFF);
  ln_kernel<1, 0><<<MTOT, 256, 0, stream>>>(out1f, ffnb, gamma, beta, (float*)d_out, nullptr);
}